// Round 1
// baseline (907.445 us; speedup 1.0000x reference)
//
#include <hip/hip_runtime.h>

#define B_ 2
#define L_ 2048
#define C_ 2048
#define H_ 16
#define HKV_ 4
#define D_ 128
#define G_ (H_ / HKV_)
#define TOK_ (B_ * L_)

typedef __bf16 bf16;
typedef __bf16 bf16x4 __attribute__((ext_vector_type(4)));
typedef __bf16 bf16x8 __attribute__((ext_vector_type(8)));
typedef float f32x4 __attribute__((ext_vector_type(4)));

// ---------------- fp32 -> bf16 conversion ----------------
__global__ void cvt_bf16(const float* __restrict__ in, bf16* __restrict__ out, int n4) {
  int stride = gridDim.x * blockDim.x;
  for (int j = blockIdx.x * blockDim.x + threadIdx.x; j < n4; j += stride) {
    float4 v = reinterpret_cast<const float4*>(in)[j];
    bf16x4 o = {(bf16)v.x, (bf16)v.y, (bf16)v.z, (bf16)v.w};
    reinterpret_cast<bf16x4*>(out)[j] = o;
  }
}

// ---------------- GEMM: C[M,N] = A[M,K] @ B[N,K]^T (bf16 in, f32 acc) ------
// 128x128 tile, BK=32, 256 threads (4 waves), each wave 64x64 (4x4 frags).
template <bool OUT_F32>
__global__ __launch_bounds__(256) void gemm_bt(
    const bf16* __restrict__ A, const bf16* __restrict__ Bm,
    void* __restrict__ Cm, int M, int N, int K) {
  __shared__ __align__(16) bf16 sA[128 * 32];
  __shared__ __align__(16) bf16 sB[128 * 32];
  const int tid = threadIdx.x;
  const int row0 = blockIdx.x * 128, col0 = blockIdx.y * 128;
  const int wid = tid >> 6, lane = tid & 63;
  const int wr = wid >> 1, wc = wid & 1;
  const int l15 = lane & 15, kk = (lane >> 4) * 8;
  f32x4 acc[4][4] = {};
  const int nk = K / 32;
  for (int kt = 0; kt < nk; ++kt) {
    uint4 ra[2], rb[2];
#pragma unroll
    for (int it = 0; it < 2; ++it) {
      int f = it * 256 + tid;
      int r = f >> 2, cch = f & 3;
      ra[it] = *reinterpret_cast<const uint4*>(A + (size_t)(row0 + r) * K + kt * 32 + cch * 8);
      rb[it] = *reinterpret_cast<const uint4*>(Bm + (size_t)(col0 + r) * K + kt * 32 + cch * 8);
    }
    __syncthreads();
#pragma unroll
    for (int it = 0; it < 2; ++it) {
      int f = it * 256 + tid;
      *reinterpret_cast<uint4*>(sA + f * 8) = ra[it];
      *reinterpret_cast<uint4*>(sB + f * 8) = rb[it];
    }
    __syncthreads();
    bf16x8 af[4], bfr[4];
#pragma unroll
    for (int m = 0; m < 4; ++m)
      af[m] = *reinterpret_cast<const bf16x8*>(sA + (wr * 64 + m * 16 + l15) * 32 + kk);
#pragma unroll
    for (int n = 0; n < 4; ++n)
      bfr[n] = *reinterpret_cast<const bf16x8*>(sB + (wc * 64 + n * 16 + l15) * 32 + kk);
#pragma unroll
    for (int m = 0; m < 4; ++m)
#pragma unroll
      for (int n = 0; n < 4; ++n)
        acc[m][n] = __builtin_amdgcn_mfma_f32_16x16x32_bf16(af[m], bfr[n], acc[m][n], 0, 0, 0);
  }
#pragma unroll
  for (int m = 0; m < 4; ++m)
#pragma unroll
    for (int n = 0; n < 4; ++n)
#pragma unroll
      for (int r = 0; r < 4; ++r) {
        int row = row0 + wr * 64 + m * 16 + (lane >> 4) * 4 + r;
        int col = col0 + wc * 64 + n * 16 + l15;
        if constexpr (OUT_F32)
          reinterpret_cast<float*>(Cm)[(size_t)row * N + col] = acc[m][n][r];
        else
          reinterpret_cast<bf16*>(Cm)[(size_t)row * N + col] = (bf16)acc[m][n][r];
      }
}

// ---------------- RMSNorm + RoPE for q/k, relayout to (B, NH, L, D) --------
__global__ void qk_norm_rope(const bf16* __restrict__ proj,  // (TOK, NH*D)
                             const float* __restrict__ normw,
                             const float* __restrict__ cosb,  // (L, 64)
                             const float* __restrict__ sinb,
                             bf16* __restrict__ out,  // (B, NH, L, D)
                             int NH) {
  int wid = (blockIdx.x * blockDim.x + threadIdx.x) >> 6;
  int lane = threadIdx.x & 63;
  int head = wid % NH, tok = wid / NH;
  int b = tok / L_, l = tok % L_;
  const bf16* p = proj + (size_t)tok * NH * D_ + head * D_;
  float t1 = (float)p[lane];
  float t2 = (float)p[lane + 64];
  float ss = t1 * t1 + t2 * t2;
#pragma unroll
  for (int off = 32; off; off >>= 1) ss += __shfl_xor(ss, off);
  float r = rsqrtf(ss * (1.0f / 128.0f) + 1e-6f);
  float n1 = t1 * r * normw[lane];
  float n2 = t2 * r * normw[lane + 64];
  float c = cosb[l * 64 + lane], s = sinb[l * 64 + lane];
  float o1 = n1 * c - n2 * s;
  float o2 = n2 * c + n1 * s;
  bf16* q = out + (((size_t)b * NH + head) * L_ + l) * D_;
  q[lane] = (bf16)o1;
  q[lane + 64] = (bf16)o2;
}

// ---------------- V transpose: (TOK, HKV*D) -> (B, HKV, D, L) --------------
__global__ void v_transpose_k(const bf16* __restrict__ vproj, bf16* __restrict__ vt) {
  int idx = blockIdx.x * blockDim.x + threadIdx.x;  // over B*HKV*D*L
  int l = idx % L_;
  int rest = idx / L_;
  int d = rest % D_;
  int rest2 = rest / D_;
  int h = rest2 % HKV_;
  int b = rest2 / HKV_;
  vt[idx] = vproj[((size_t)(b * L_ + l) * HKV_ + h) * D_ + d];
}

// ---------------- Flash attention, block-causal (256-blocks), GQA ----------
// 1 wave per 16 query rows of one (b,h). Visible keys = multiple of 256.
__global__ __launch_bounds__(64) void attn16(
    const bf16* __restrict__ Q,   // (B,H,L,D)
    const bf16* __restrict__ Kb_, // (B,HKV,L,D)
    const bf16* __restrict__ Vt,  // (B,HKV,D,L)
    bf16* __restrict__ AO) {      // (B,L,H,D)
  __shared__ __align__(16) bf16 sp[16 * 32];
  const int lane = threadIdx.x;
  const int bid = blockIdx.x;
  const int qt = bid % (L_ / 16);
  const int h = (bid / (L_ / 16)) % H_;
  const int b = bid / (L_ / 16) / H_;
  const int kvh = h / G_;
  const int qrow0 = qt * 16;
  const int l15 = lane & 15, kk = (lane >> 4) * 8;
  const bf16* qb = Q + (((size_t)b * H_ + h) * L_ + qrow0) * D_;
  const bf16* kb = Kb_ + ((size_t)b * HKV_ + kvh) * L_ * D_;
  const bf16* vb = Vt + ((size_t)b * HKV_ + kvh) * D_ * (size_t)L_;
  bf16x8 qf[4];
#pragma unroll
  for (int c = 0; c < 4; ++c)
    qf[c] = *reinterpret_cast<const bf16x8*>(qb + l15 * D_ + c * 32 + kk);
  f32x4 acc[8] = {};
  float mrun[4], lrun[4];
#pragma unroll
  for (int r = 0; r < 4; ++r) { mrun[r] = -1e30f; lrun[r] = 0.f; }
  const int nkc = ((qrow0 / 256) + 1) * 256 / 32;
  const float scale = 0.08838834764831845f;  // 128^-0.5
  for (int kc = 0; kc < nkc; ++kc) {
    f32x4 s[2];
#pragma unroll
    for (int hh = 0; hh < 2; ++hh) {
      int kcol0 = kc * 32 + hh * 16;
      f32x4 st = {};
#pragma unroll
      for (int c = 0; c < 4; ++c) {
        bf16x8 kf = *reinterpret_cast<const bf16x8*>(kb + (size_t)(kcol0 + l15) * D_ + c * 32 + kk);
        st = __builtin_amdgcn_mfma_f32_16x16x32_bf16(qf[c], kf, st, 0, 0, 0);
      }
      s[hh] = st * scale;
    }
    float pm[4], prob0[4], prob1[4], rowsum[4];
#pragma unroll
    for (int r = 0; r < 4; ++r) pm[r] = fmaxf(s[0][r], s[1][r]);
#pragma unroll
    for (int off = 1; off < 16; off <<= 1)
#pragma unroll
      for (int r = 0; r < 4; ++r) pm[r] = fmaxf(pm[r], __shfl_xor(pm[r], off));
#pragma unroll
    for (int r = 0; r < 4; ++r) {
      float mnew = fmaxf(mrun[r], pm[r]);
      float sc = expf(mrun[r] - mnew);
      mrun[r] = mnew;
      lrun[r] *= sc;
#pragma unroll
      for (int f = 0; f < 8; ++f) acc[f][r] *= sc;
      prob0[r] = expf(s[0][r] - mnew);
      prob1[r] = expf(s[1][r] - mnew);
      rowsum[r] = prob0[r] + prob1[r];
    }
#pragma unroll
    for (int off = 1; off < 16; off <<= 1)
#pragma unroll
      for (int r = 0; r < 4; ++r) rowsum[r] += __shfl_xor(rowsum[r], off);
#pragma unroll
    for (int r = 0; r < 4; ++r) lrun[r] += rowsum[r];
    __syncthreads();
#pragma unroll
    for (int r = 0; r < 4; ++r) {
      int prow = (lane >> 4) * 4 + r;
      sp[prow * 32 + l15] = (bf16)prob0[r];
      sp[prow * 32 + 16 + l15] = (bf16)prob1[r];
    }
    __syncthreads();
    bf16x8 pf = *reinterpret_cast<const bf16x8*>(sp + l15 * 32 + kk);
#pragma unroll
    for (int f = 0; f < 8; ++f) {
      bf16x8 vf = *reinterpret_cast<const bf16x8*>(vb + (size_t)(f * 16 + l15) * L_ + kc * 32 + kk);
      acc[f] = __builtin_amdgcn_mfma_f32_16x16x32_bf16(pf, vf, acc[f], 0, 0, 0);
    }
  }
#pragma unroll
  for (int f = 0; f < 8; ++f)
#pragma unroll
    for (int r = 0; r < 4; ++r) {
      int row = qrow0 + (lane >> 4) * 4 + r;
      int col = f * 16 + l15;
      AO[((size_t)(b * L_ + row) * H_ + h) * D_ + col] = (bf16)(acc[f][r] / lrun[r]);
    }
}

// ---------------- launch ----------------
extern "C" void kernel_launch(void* const* d_in, const int* in_sizes, int n_in,
                              void* d_out, int out_size, void* d_ws, size_t ws_size,
                              hipStream_t stream) {
  const float* x = (const float*)d_in[0];
  const float* Wq = (const float*)d_in[1];
  const float* Wk = (const float*)d_in[2];
  const float* Wv = (const float*)d_in[3];
  const float* Wo = (const float*)d_in[4];
  const float* qnw = (const float*)d_in[5];
  const float* knw = (const float*)d_in[6];
  const float* rc = (const float*)d_in[7];
  const float* rs = (const float*)d_in[8];
  float* out = (float*)d_out;

  char* ws = (char*)d_ws;
  bf16* xb = (bf16*)ws;                 ws += (size_t)TOK_ * C_ * 2;        // 16.8 MB
  bf16* wqb = (bf16*)ws;                ws += (size_t)(H_ * D_) * C_ * 2;   // 8.4 MB
  bf16* wkb = (bf16*)ws;                ws += (size_t)(HKV_ * D_) * C_ * 2; // 2.1 MB
  bf16* wvb = (bf16*)ws;                ws += (size_t)(HKV_ * D_) * C_ * 2; // 2.1 MB
  bf16* wob = (bf16*)ws;                ws += (size_t)C_ * (H_ * D_) * 2;   // 8.4 MB
  bf16* qproj = (bf16*)ws;              ws += (size_t)TOK_ * H_ * D_ * 2;   // 16.8 MB
  bf16* kproj = (bf16*)ws;              ws += (size_t)TOK_ * HKV_ * D_ * 2; // 4.2 MB
  bf16* vproj = (bf16*)ws;              ws += (size_t)TOK_ * HKV_ * D_ * 2; // 4.2 MB
  bf16* Qb = (bf16*)ws;                 ws += (size_t)TOK_ * H_ * D_ * 2;   // 16.8 MB
  bf16* Kb = (bf16*)ws;                 ws += (size_t)TOK_ * HKV_ * D_ * 2; // 4.2 MB
  bf16* Vtb = (bf16*)ws;                ws += (size_t)TOK_ * HKV_ * D_ * 2; // 4.2 MB
  bf16* AOb = xb;  // alias: x (bf16) is dead after the three projections

  auto cvt = [&](const float* src, bf16* dst, size_t n) {
    int n4 = (int)(n / 4);
    int grid = (n4 + 255) / 256;
    if (grid > 4096) grid = 4096;
    cvt_bf16<<<grid, 256, 0, stream>>>(src, dst, n4);
  };
  cvt(x, xb, (size_t)TOK_ * C_);
  cvt(Wq, wqb, (size_t)H_ * D_ * C_);
  cvt(Wk, wkb, (size_t)HKV_ * D_ * C_);
  cvt(Wv, wvb, (size_t)HKV_ * D_ * C_);
  cvt(Wo, wob, (size_t)C_ * H_ * D_);

  gemm_bt<false><<<dim3(TOK_ / 128, (H_ * D_) / 128), 256, 0, stream>>>(
      xb, wqb, qproj, TOK_, H_ * D_, C_);
  gemm_bt<false><<<dim3(TOK_ / 128, (HKV_ * D_) / 128), 256, 0, stream>>>(
      xb, wkb, kproj, TOK_, HKV_ * D_, C_);
  gemm_bt<false><<<dim3(TOK_ / 128, (HKV_ * D_) / 128), 256, 0, stream>>>(
      xb, wvb, vproj, TOK_, HKV_ * D_, C_);

  qk_norm_rope<<<(TOK_ * H_) / 4, 256, 0, stream>>>(qproj, qnw, rc, rs, Qb, H_);
  qk_norm_rope<<<(TOK_ * HKV_) / 4, 256, 0, stream>>>(kproj, knw, rc, rs, Kb, HKV_);
  v_transpose_k<<<(B_ * HKV_ * D_ * L_) / 256, 256, 0, stream>>>(vproj, Vtb);

  attn16<<<B_ * H_ * (L_ / 16), 64, 0, stream>>>(Qb, Kb, Vtb, AOb);

  gemm_bt<true><<<dim3(TOK_ / 128, C_ / 128), 256, 0, stream>>>(
      AOb, wob, out, TOK_, C_, H_ * D_);
}

// Round 2
// 321.113 us; speedup vs baseline: 2.8259x; 2.8259x over previous
//
#include <hip/hip_runtime.h>

#define B_ 2
#define L_ 2048
#define C_ 2048
#define H_ 16
#define HKV_ 4
#define D_ 128
#define G_ (H_ / HKV_)
#define TOK_ (B_ * L_)
#define NQKV_ 3072  // H*D + 2*HKV*D

typedef __bf16 bf16;
typedef __bf16 bf16x4 __attribute__((ext_vector_type(4)));
typedef __bf16 bf16x8 __attribute__((ext_vector_type(8)));
typedef float f32x4 __attribute__((ext_vector_type(4)));

__device__ inline void gload16(const void* g, void* l) {
  __builtin_amdgcn_global_load_lds(
      (const __attribute__((address_space(1))) void*)g,
      (__attribute__((address_space(3))) void*)l, 16, 0, 0);
}

// ---------------- fp32 -> bf16 conversion ----------------
__global__ void cvt_bf16(const float* __restrict__ in, bf16* __restrict__ out, int n4) {
  int stride = gridDim.x * blockDim.x;
  for (int j = blockIdx.x * blockDim.x + threadIdx.x; j < n4; j += stride) {
    float4 v = reinterpret_cast<const float4*>(in)[j];
    bf16x4 o = {(bf16)v.x, (bf16)v.y, (bf16)v.z, (bf16)v.w};
    reinterpret_cast<bf16x4*>(out)[j] = o;
  }
}

// ---------------- GEMM: C[M,N] = A[M,K] @ B[N,K]^T (bf16 in, f32 acc) ------
// 128x128 tile, BK=32, 4 waves, global_load_lds staging (m97 structure).
template <bool OUT_F32>
__global__ __launch_bounds__(256) void gemm_bt(
    const bf16* __restrict__ A, const bf16* __restrict__ Bm,
    void* __restrict__ Cm, int M, int N, int K) {
  __shared__ __align__(16) bf16 sA[128 * 32];
  __shared__ __align__(16) bf16 sB[128 * 32];
  const int tid = threadIdx.x;
  const int row0 = blockIdx.x * 128, col0 = blockIdx.y * 128;
  const int wid = tid >> 6, lane = tid & 63;
  const int wr = wid >> 1, wc = wid & 1;
  const int l15 = lane & 15, kk = (lane >> 4) * 8;
  f32x4 acc[4][4] = {};
  const int nk = K / 32;
  const int f0 = tid;          // per-lane chunk id for it=0
  const int r0 = f0 >> 2, c0 = f0 & 3;
  const int f1 = 256 + tid;
  const int r1 = f1 >> 2, c1 = f1 & 3;
  const int ldsA0 = (wid * 64) * 8, ldsA1 = (256 + wid * 64) * 8;
  for (int kt = 0; kt < nk; ++kt) {
    __syncthreads();
    gload16(A + (size_t)(row0 + r0) * K + kt * 32 + c0 * 8, sA + ldsA0);
    gload16(A + (size_t)(row0 + r1) * K + kt * 32 + c1 * 8, sA + ldsA1);
    gload16(Bm + (size_t)(col0 + r0) * K + kt * 32 + c0 * 8, sB + ldsA0);
    gload16(Bm + (size_t)(col0 + r1) * K + kt * 32 + c1 * 8, sB + ldsA1);
    __syncthreads();
    bf16x8 af[4], bfr[4];
#pragma unroll
    for (int m = 0; m < 4; ++m)
      af[m] = *reinterpret_cast<const bf16x8*>(sA + (wr * 64 + m * 16 + l15) * 32 + kk);
#pragma unroll
    for (int n = 0; n < 4; ++n)
      bfr[n] = *reinterpret_cast<const bf16x8*>(sB + (wc * 64 + n * 16 + l15) * 32 + kk);
#pragma unroll
    for (int m = 0; m < 4; ++m)
#pragma unroll
      for (int n = 0; n < 4; ++n)
        acc[m][n] = __builtin_amdgcn_mfma_f32_16x16x32_bf16(af[m], bfr[n], acc[m][n], 0, 0, 0);
  }
#pragma unroll
  for (int m = 0; m < 4; ++m)
#pragma unroll
    for (int n = 0; n < 4; ++n)
#pragma unroll
      for (int r = 0; r < 4; ++r) {
        int row = row0 + wr * 64 + m * 16 + (lane >> 4) * 4 + r;
        int col = col0 + wc * 64 + n * 16 + l15;
        if constexpr (OUT_F32)
          reinterpret_cast<float*>(Cm)[(size_t)row * N + col] = acc[m][n][r];
        else
          reinterpret_cast<bf16*>(Cm)[(size_t)row * N + col] = (bf16)acc[m][n][r];
      }
}

// ---------------- RMSNorm + RoPE for K, relayout to (B, HKV, L, D) ---------
__global__ void k_norm_rope(const bf16* __restrict__ proj,  // (TOK, NQKV)
                            const float* __restrict__ normw,
                            const float* __restrict__ cosb,  // (L, 64)
                            const float* __restrict__ sinb,
                            bf16* __restrict__ out) {  // (B, HKV, L, D)
  int wid = (blockIdx.x * blockDim.x + threadIdx.x) >> 6;
  int lane = threadIdx.x & 63;
  int head = wid & 3, tok = wid >> 2;
  int b = tok / L_, l = tok % L_;
  const bf16* p = proj + (size_t)tok * NQKV_ + H_ * D_ + head * D_;
  float t1 = (float)p[lane];
  float t2 = (float)p[lane + 64];
  float ss = t1 * t1 + t2 * t2;
#pragma unroll
  for (int off = 32; off; off >>= 1) ss += __shfl_xor(ss, off);
  float r = rsqrtf(ss * (1.0f / 128.0f) + 1e-6f);
  float n1 = t1 * r * normw[lane];
  float n2 = t2 * r * normw[lane + 64];
  float c = cosb[l * 64 + lane], s = sinb[l * 64 + lane];
  bf16* q = out + (((size_t)b * HKV_ + head) * L_ + l) * D_;
  q[lane] = (bf16)(n1 * c - n2 * s);
  q[lane + 64] = (bf16)(n2 * c + n1 * s);
}

// ---------------- V transpose (LDS-tiled): (TOK,NQKV col 2560+) -> (B,HKV,D,L)
__global__ __launch_bounds__(256) void v_transpose(const bf16* __restrict__ proj,
                                                   bf16* __restrict__ vt) {
  __shared__ __align__(16) bf16 sT[64 * 136];
  const int t = threadIdx.x;
  const int l0 = blockIdx.x * 64;
  const int bk = blockIdx.y;  // b*HKV+h
  const bf16* src = proj + (size_t)((bk >> 2) * L_ + l0) * NQKV_ + (H_ + HKV_) * D_ + (bk & 3) * D_;
#pragma unroll
  for (int c = 0; c < 4; ++c) {
    int idx = c * 256 + t;
    int l = idx >> 4, dc = idx & 15;
    bf16x8 v = *reinterpret_cast<const bf16x8*>(src + (size_t)l * NQKV_ + dc * 8);
    *reinterpret_cast<bf16x8*>((char*)sT + l * 272 + ((dc ^ (l >> 3)) << 4)) = v;
  }
  __syncthreads();
  bf16* dst = vt + (size_t)bk * D_ * L_ + l0;
#pragma unroll
  for (int c = 0; c < 4; ++c) {
    int idx = c * 256 + t;
    int d = idx >> 3, lg = idx & 7;
    bf16x8 o;
#pragma unroll
    for (int j = 0; j < 8; ++j) {
      int l = lg * 8 + j;
      o[j] = *reinterpret_cast<const bf16*>((char*)sT + l * 272 + (((d >> 3) ^ lg) << 4) + (d & 7) * 2);
    }
    *reinterpret_cast<bf16x8*>(dst + (size_t)d * L_ + lg * 8) = o;
  }
}

// ---------------- Fused flash attention, block-causal, GQA -----------------
// Block: 512 threads = 8 waves = 4 heads x 2 q-subtiles(16 rows) over 32 q rows.
// K/V tiles (64 keys) staged in LDS via global_load_lds, XOR-swizzled reads.
__global__ __launch_bounds__(512, 4) void attn_fused(
    const bf16* __restrict__ QKV,  // (TOK, NQKV) raw projections
    const bf16* __restrict__ Kn,   // (B,HKV,L,D) normed+roped
    const bf16* __restrict__ Vt,   // (B,HKV,D,L)
    const float* __restrict__ qnw,
    const float* __restrict__ cosb, const float* __restrict__ sinb,
    bf16* __restrict__ AO) {  // (B,L,H,D)
  __shared__ __align__(16) bf16 sK[64 * 128];
  __shared__ __align__(16) bf16 sV[128 * 64];
  __shared__ __align__(16) bf16 sP[8 * 16 * 72];
  const int tid = threadIdx.x;
  const int wid = tid >> 6, lane = tid & 63;
  const int qt = blockIdx.x;   // 32 q rows per block
  const int bk = blockIdx.y;   // b*HKV + kvh
  const int b = bk >> 2;
  const int hl = wid & 3, qs = wid >> 2;
  const int h = (bk & 3) * G_ + hl;
  const int qrow0 = qt * 32 + qs * 16;
  const int l15 = lane & 15, g4 = lane >> 4, kk = g4 * 8;
  const int swz = (l15 & 7) << 4;

  // ---- fused Q: RMSNorm + RoPE into bf16 fragments (row = qrow0 + l15) ----
  const int qrow = qrow0 + l15;
  const bf16* qsrc = QKV + (size_t)(b * L_ + qrow) * NQKV_ + h * D_;
  float t[4][8];
  float ss = 0.f;
#pragma unroll
  for (int c = 0; c < 4; ++c) {
    bf16x8 v = *reinterpret_cast<const bf16x8*>(qsrc + c * 32 + kk);
#pragma unroll
    for (int j = 0; j < 8; ++j) { t[c][j] = (float)v[j]; ss += t[c][j] * t[c][j]; }
  }
  ss += __shfl_xor(ss, 16);
  ss += __shfl_xor(ss, 32);
  const float rr = rsqrtf(ss * (1.0f / 128.0f) + 1e-6f);
  bf16x8 qf[4];
#pragma unroll
  for (int c = 0; c < 2; ++c)
#pragma unroll
    for (int j = 0; j < 8; ++j) {
      int i = c * 32 + kk + j;
      float n1 = t[c][j] * rr * qnw[i];
      float n2 = t[c + 2][j] * rr * qnw[i + 64];
      float cs = cosb[qrow * 64 + i], sn = sinb[qrow * 64 + i];
      qf[c][j] = (bf16)(n1 * cs - n2 * sn);
      qf[c + 2][j] = (bf16)(n2 * cs + n1 * sn);
    }

  const bf16* kb = Kn + (size_t)bk * L_ * D_;
  const bf16* vb = Vt + (size_t)bk * D_ * L_;
  bf16* myP = sP + wid * 16 * 72;
  f32x4 acc[8] = {};
  float mrow[4], lrow[4];
#pragma unroll
  for (int r = 0; r < 4; ++r) { mrow[r] = -1e30f; lrow[r] = 0.f; }
  const int ntiles = ((qt >> 3) + 1) * 4;
  constexpr float SCL = 0.12752650038632816f;  // 128^-0.5 * log2(e)

  // per-thread staging coordinates
  const int i0 = tid, i1 = 512 + tid;
  const int kr0 = i0 >> 4, kc0 = i0 & 15, kr1 = i1 >> 4, kc1 = i1 & 15;
  const int dr0 = i0 >> 3, vc0 = i0 & 7, dr1 = i1 >> 3, vc1 = i1 & 7;
  const int ldsB0 = (wid * 64) * 8, ldsB1 = (512 + wid * 64) * 8;

  for (int kt = 0; kt < ntiles; ++kt) {
    __syncthreads();
    gload16(kb + (size_t)(kt * 64 + kr0) * D_ + ((kc0 ^ (kr0 & 7)) * 8), sK + ldsB0);
    gload16(kb + (size_t)(kt * 64 + kr1) * D_ + ((kc1 ^ (kr1 & 7)) * 8), sK + ldsB1);
    gload16(vb + (size_t)dr0 * L_ + kt * 64 + ((vc0 ^ (dr0 & 7)) * 8), sV + ldsB0);
    gload16(vb + (size_t)dr1 * L_ + kt * 64 + ((vc1 ^ (dr1 & 7)) * 8), sV + ldsB1);
    __syncthreads();
    // --- QK^T ---
    f32x4 s[4];
#pragma unroll
    for (int n = 0; n < 4; ++n) {
      f32x4 st = {};
#pragma unroll
      for (int c = 0; c < 4; ++c) {
        int byte = ((n * 16 + l15) * 128 + c * 32 + kk) * 2 ^ swz;
        bf16x8 kf = *reinterpret_cast<const bf16x8*>((const char*)sK + byte);
        st = __builtin_amdgcn_mfma_f32_16x16x32_bf16(qf[c], kf, st, 0, 0, 0);
      }
      s[n] = st * SCL;
    }
    // --- online softmax (log2 domain) ---
    float pm[4], rsum[4];
#pragma unroll
    for (int r = 0; r < 4; ++r)
      pm[r] = fmaxf(fmaxf(s[0][r], s[1][r]), fmaxf(s[2][r], s[3][r]));
#pragma unroll
    for (int off = 1; off < 16; off <<= 1)
#pragma unroll
      for (int r = 0; r < 4; ++r) pm[r] = fmaxf(pm[r], __shfl_xor(pm[r], off));
#pragma unroll
    for (int r = 0; r < 4; ++r) {
      float mnew = fmaxf(mrow[r], pm[r]);
      float resc = exp2f(mrow[r] - mnew);
      mrow[r] = mnew;
      lrow[r] *= resc;
#pragma unroll
      for (int f = 0; f < 8; ++f) acc[f][r] *= resc;
      float rs = 0.f;
#pragma unroll
      for (int n = 0; n < 4; ++n) {
        float p = exp2f(s[n][r] - mnew);
        s[n][r] = p;
        rs += p;
      }
      rsum[r] = rs;
    }
#pragma unroll
    for (int off = 1; off < 16; off <<= 1)
#pragma unroll
      for (int r = 0; r < 4; ++r) rsum[r] += __shfl_xor(rsum[r], off);
#pragma unroll
    for (int r = 0; r < 4; ++r) lrow[r] += rsum[r];
    // --- P -> LDS (wave-private, no barrier) ---
#pragma unroll
    for (int n = 0; n < 4; ++n)
#pragma unroll
      for (int r = 0; r < 4; ++r)
        myP[(g4 * 4 + r) * 72 + n * 16 + l15] = (bf16)s[n][r];
    bf16x8 pf0 = *reinterpret_cast<const bf16x8*>(myP + l15 * 72 + kk);
    bf16x8 pf1 = *reinterpret_cast<const bf16x8*>(myP + l15 * 72 + 32 + kk);
    // --- PV ---
#pragma unroll
    for (int f = 0; f < 8; ++f) {
      int byte0 = ((f * 16 + l15) * 64 + kk) * 2 ^ swz;
      bf16x8 vf0 = *reinterpret_cast<const bf16x8*>((const char*)sV + byte0);
      acc[f] = __builtin_amdgcn_mfma_f32_16x16x32_bf16(pf0, vf0, acc[f], 0, 0, 0);
      int byte1 = ((f * 16 + l15) * 64 + 32 + kk) * 2 ^ swz;
      bf16x8 vf1 = *reinterpret_cast<const bf16x8*>((const char*)sV + byte1);
      acc[f] = __builtin_amdgcn_mfma_f32_16x16x32_bf16(pf1, vf1, acc[f], 0, 0, 0);
    }
  }
  // --- epilogue ---
#pragma unroll
  for (int f = 0; f < 8; ++f)
#pragma unroll
    for (int r = 0; r < 4; ++r) {
      int row = qrow0 + g4 * 4 + r;
      AO[((size_t)(b * L_ + row) * H_ + h) * D_ + f * 16 + l15] = (bf16)(acc[f][r] / lrow[r]);
    }
}

// ---------------- launch ----------------
extern "C" void kernel_launch(void* const* d_in, const int* in_sizes, int n_in,
                              void* d_out, int out_size, void* d_ws, size_t ws_size,
                              hipStream_t stream) {
  const float* x = (const float*)d_in[0];
  const float* Wq = (const float*)d_in[1];
  const float* Wk = (const float*)d_in[2];
  const float* Wv = (const float*)d_in[3];
  const float* Wo = (const float*)d_in[4];
  const float* qnw = (const float*)d_in[5];
  const float* knw = (const float*)d_in[6];
  const float* rc = (const float*)d_in[7];
  const float* rs = (const float*)d_in[8];
  float* out = (float*)d_out;

  char* ws = (char*)d_ws;
  bf16* xb = (bf16*)ws;    ws += (size_t)TOK_ * C_ * 2;
  bf16* wqb = (bf16*)ws;   ws += (size_t)(H_ * D_) * C_ * 2;   // wq/wk/wv contiguous!
  bf16* wkb = (bf16*)ws;   ws += (size_t)(HKV_ * D_) * C_ * 2;
  bf16* wvb = (bf16*)ws;   ws += (size_t)(HKV_ * D_) * C_ * 2;
  bf16* wob = (bf16*)ws;   ws += (size_t)C_ * (H_ * D_) * 2;
  bf16* qkv = (bf16*)ws;   ws += (size_t)TOK_ * NQKV_ * 2;
  bf16* Kb = (bf16*)ws;    ws += (size_t)TOK_ * HKV_ * D_ * 2;
  bf16* Vtb = (bf16*)ws;   ws += (size_t)TOK_ * HKV_ * D_ * 2;
  bf16* AOb = xb;  // alias: xb dead after projection GEMM

  auto cvt = [&](const float* src, bf16* dst, size_t n) {
    int n4 = (int)(n / 4);
    int grid = (n4 + 255) / 256;
    if (grid > 4096) grid = 4096;
    cvt_bf16<<<grid, 256, 0, stream>>>(src, dst, n4);
  };
  cvt(x, xb, (size_t)TOK_ * C_);
  cvt(Wq, wqb, (size_t)H_ * D_ * C_);
  cvt(Wk, wkb, (size_t)HKV_ * D_ * C_);
  cvt(Wv, wvb, (size_t)HKV_ * D_ * C_);
  cvt(Wo, wob, (size_t)C_ * H_ * D_);

  // fused QKV projection: N = 3072 (wq,wk,wv rows contiguous)
  gemm_bt<false><<<dim3(TOK_ / 128, NQKV_ / 128), 256, 0, stream>>>(
      xb, wqb, qkv, TOK_, NQKV_, C_);

  k_norm_rope<<<(TOK_ * HKV_) / 4, 256, 0, stream>>>(qkv, knw, rc, rs, Kb);
  v_transpose<<<dim3(L_ / 64, B_ * HKV_), 256, 0, stream>>>(qkv, Vtb);

  attn_fused<<<dim3(L_ / 32, B_ * HKV_), 512, 0, stream>>>(
      qkv, Kb, Vtb, qnw, rc, rs, AOb);

  gemm_bt<true><<<dim3(TOK_ / 128, C_ / 128), 256, 0, stream>>>(
      AOb, wob, out, TOK_, C_, H_ * D_);
}

// Round 3
// 264.291 us; speedup vs baseline: 3.4335x; 1.2150x over previous
//
#include <hip/hip_runtime.h>

#define B_ 2
#define L_ 2048
#define C_ 2048
#define H_ 16
#define HKV_ 4
#define D_ 128
#define G_ (H_ / HKV_)
#define TOK_ (B_ * L_)
#define NQKV_ 3072  // H*D + 2*HKV*D

typedef __bf16 bf16;
typedef __bf16 bf16x4 __attribute__((ext_vector_type(4)));
typedef __bf16 bf16x8 __attribute__((ext_vector_type(8)));
typedef float f32x4 __attribute__((ext_vector_type(4)));

__device__ inline void gload16(const void* g, void* l) {
  __builtin_amdgcn_global_load_lds(
      (const __attribute__((address_space(1))) void*)g,
      (__attribute__((address_space(3))) void*)l, 16, 0, 0);
}

// ---------------- fp32 -> bf16 conversion ----------------
__global__ void cvt_bf16(const float* __restrict__ in, bf16* __restrict__ out, int n4) {
  int stride = gridDim.x * blockDim.x;
  for (int j = blockIdx.x * blockDim.x + threadIdx.x; j < n4; j += stride) {
    float4 v = reinterpret_cast<const float4*>(in)[j];
    bf16x4 o = {(bf16)v.x, (bf16)v.y, (bf16)v.z, (bf16)v.w};
    reinterpret_cast<bf16x4*>(out)[j] = o;
  }
}

// ---------------- GEMM: C[M,N] = A[M,K] @ B[N,K]^T (bf16 in, f32 acc) ------
// 128x128 tile, BK=32, 4 waves, global_load_lds staging (m97 structure).
template <bool OUT_F32>
__global__ __launch_bounds__(256) void gemm_bt(
    const bf16* __restrict__ A, const bf16* __restrict__ Bm,
    void* __restrict__ Cm, int M, int N, int K) {
  __shared__ __align__(16) bf16 sA[128 * 32];
  __shared__ __align__(16) bf16 sB[128 * 32];
  const int tid = threadIdx.x;
  const int row0 = blockIdx.x * 128, col0 = blockIdx.y * 128;
  const int wid = tid >> 6, lane = tid & 63;
  const int wr = wid >> 1, wc = wid & 1;
  const int l15 = lane & 15, kk = (lane >> 4) * 8;
  f32x4 acc[4][4] = {};
  const int nk = K / 32;
  const int f0 = tid;
  const int r0 = f0 >> 2, c0 = f0 & 3;
  const int f1 = 256 + tid;
  const int r1 = f1 >> 2, c1 = f1 & 3;
  const int ldsA0 = (wid * 64) * 8, ldsA1 = (256 + wid * 64) * 8;
  for (int kt = 0; kt < nk; ++kt) {
    __syncthreads();
    gload16(A + (size_t)(row0 + r0) * K + kt * 32 + c0 * 8, sA + ldsA0);
    gload16(A + (size_t)(row0 + r1) * K + kt * 32 + c1 * 8, sA + ldsA1);
    gload16(Bm + (size_t)(col0 + r0) * K + kt * 32 + c0 * 8, sB + ldsA0);
    gload16(Bm + (size_t)(col0 + r1) * K + kt * 32 + c1 * 8, sB + ldsA1);
    __syncthreads();
    bf16x8 af[4], bfr[4];
#pragma unroll
    for (int m = 0; m < 4; ++m)
      af[m] = *reinterpret_cast<const bf16x8*>(sA + (wr * 64 + m * 16 + l15) * 32 + kk);
#pragma unroll
    for (int n = 0; n < 4; ++n)
      bfr[n] = *reinterpret_cast<const bf16x8*>(sB + (wc * 64 + n * 16 + l15) * 32 + kk);
#pragma unroll
    for (int m = 0; m < 4; ++m)
#pragma unroll
      for (int n = 0; n < 4; ++n)
        acc[m][n] = __builtin_amdgcn_mfma_f32_16x16x32_bf16(af[m], bfr[n], acc[m][n], 0, 0, 0);
  }
#pragma unroll
  for (int m = 0; m < 4; ++m)
#pragma unroll
    for (int n = 0; n < 4; ++n)
#pragma unroll
      for (int r = 0; r < 4; ++r) {
        int row = row0 + wr * 64 + m * 16 + (lane >> 4) * 4 + r;
        int col = col0 + wc * 64 + n * 16 + l15;
        if constexpr (OUT_F32)
          reinterpret_cast<float*>(Cm)[(size_t)row * N + col] = acc[m][n][r];
        else
          reinterpret_cast<bf16*>(Cm)[(size_t)row * N + col] = (bf16)acc[m][n][r];
      }
}

// ---------------- RMSNorm + RoPE for K, relayout to (B, HKV, L, D) ---------
__global__ void k_norm_rope(const bf16* __restrict__ proj,  // (TOK, NQKV)
                            const float* __restrict__ normw,
                            const float* __restrict__ cosb,  // (L, 64)
                            const float* __restrict__ sinb,
                            bf16* __restrict__ out) {  // (B, HKV, L, D)
  int wid = (blockIdx.x * blockDim.x + threadIdx.x) >> 6;
  int lane = threadIdx.x & 63;
  int head = wid & 3, tok = wid >> 2;
  int b = tok / L_, l = tok % L_;
  const bf16* p = proj + (size_t)tok * NQKV_ + H_ * D_ + head * D_;
  float t1 = (float)p[lane];
  float t2 = (float)p[lane + 64];
  float ss = t1 * t1 + t2 * t2;
#pragma unroll
  for (int off = 32; off; off >>= 1) ss += __shfl_xor(ss, off);
  float r = rsqrtf(ss * (1.0f / 128.0f) + 1e-6f);
  float n1 = t1 * r * normw[lane];
  float n2 = t2 * r * normw[lane + 64];
  float c = cosb[l * 64 + lane], s = sinb[l * 64 + lane];
  bf16* q = out + (((size_t)b * HKV_ + head) * L_ + l) * D_;
  q[lane] = (bf16)(n1 * c - n2 * s);
  q[lane + 64] = (bf16)(n2 * c + n1 * s);
}

// ---------------- V transpose (LDS-tiled): (TOK,NQKV col 2560+) -> (B,HKV,D,L)
__global__ __launch_bounds__(256) void v_transpose(const bf16* __restrict__ proj,
                                                   bf16* __restrict__ vt) {
  __shared__ __align__(16) bf16 sT[64 * 136];
  const int t = threadIdx.x;
  const int l0 = blockIdx.x * 64;
  const int bk = blockIdx.y;  // b*HKV+h
  const bf16* src = proj + (size_t)((bk >> 2) * L_ + l0) * NQKV_ + (H_ + HKV_) * D_ + (bk & 3) * D_;
#pragma unroll
  for (int c = 0; c < 4; ++c) {
    int idx = c * 256 + t;
    int l = idx >> 4, dc = idx & 15;
    bf16x8 v = *reinterpret_cast<const bf16x8*>(src + (size_t)l * NQKV_ + dc * 8);
    *reinterpret_cast<bf16x8*>((char*)sT + l * 272 + ((dc ^ (l >> 3)) << 4)) = v;
  }
  __syncthreads();
  bf16* dst = vt + (size_t)bk * D_ * L_ + l0;
#pragma unroll
  for (int c = 0; c < 4; ++c) {
    int idx = c * 256 + t;
    int d = idx >> 3, lg = idx & 7;
    bf16x8 o;
#pragma unroll
    for (int j = 0; j < 8; ++j) {
      int l = lg * 8 + j;
      o[j] = *reinterpret_cast<const bf16*>((char*)sT + l * 272 + (((d >> 3) ^ lg) << 4) + (d & 7) * 2);
    }
    *reinterpret_cast<bf16x8*>(dst + (size_t)d * L_ + lg * 8) = o;
  }
}

// ---------------- Fused flash attention, block-causal, GQA -----------------
// 512 thr = 8 waves = 4 heads x 2 q-subtiles(16 rows) over 32 q rows.
// Double-buffered K/V tiles (64 keys) via global_load_lds, XOR-swizzled.
// Grid 1-D: bk = bid&7 (XCD-locality for K/V), qt reversed (LPT balance).
__global__ __launch_bounds__(512, 4) void attn_fused(
    const bf16* __restrict__ QKV,  // (TOK, NQKV) raw projections
    const bf16* __restrict__ Kn,   // (B,HKV,L,D) normed+roped
    const bf16* __restrict__ Vt,   // (B,HKV,D,L)
    const float* __restrict__ qnw,
    const float* __restrict__ cosb, const float* __restrict__ sinb,
    bf16* __restrict__ AO) {  // (B,L,H,D)
  __shared__ __align__(16) bf16 sK[2][64 * 128];
  __shared__ __align__(16) bf16 sV[2][64 * 128];
  __shared__ __align__(16) bf16 sP[8 * 16 * 64];
  const int tid = threadIdx.x;
  const int wid = tid >> 6, lane = tid & 63;
  const int bid = blockIdx.x;
  const int bk = bid & 7;          // same-bk blocks land on same XCD (bid%8)
  const int qt = 63 - (bid >> 3);  // longest blocks first
  const int b = bk >> 2;
  const int hl = wid & 3, qs = wid >> 2;
  const int h = (bk & 3) * G_ + hl;
  const int qrow0 = qt * 32 + qs * 16;
  const int l15 = lane & 15, g4 = lane >> 4, kk = g4 * 8;

  // ---- fused Q: load + RMSNorm + RoPE (row = qrow0 + l15) ----
  const int qrow = qrow0 + l15;
  const bf16* qsrc = QKV + (size_t)(b * L_ + qrow) * NQKV_ + h * D_;
  float t[4][8];
  float ss = 0.f;
#pragma unroll
  for (int c = 0; c < 4; ++c) {
    bf16x8 v = *reinterpret_cast<const bf16x8*>(qsrc + c * 32 + kk);
#pragma unroll
    for (int j = 0; j < 8; ++j) { t[c][j] = (float)v[j]; ss += t[c][j] * t[c][j]; }
  }

  // staging coordinates (pre-swizzled global sources, linear LDS dest)
  const int kr0 = tid >> 4, kc0 = tid & 15;
  const int kr1 = 32 + kr0;
  const int vr0 = tid >> 3, vc0 = tid & 7;
  const int vr1 = 64 + vr0;
  const bf16* kb = Kn + (size_t)bk * L_ * D_;
  const bf16* vb = Vt + (size_t)bk * D_ * (size_t)L_;
  const bf16* kp0 = kb + (size_t)kr0 * D_ + ((kc0 ^ (kr0 & 7)) * 8);
  const bf16* kp1 = kb + (size_t)kr1 * D_ + ((kc0 ^ (kr1 & 7)) * 8);
  const bf16* vp0 = vb + (size_t)vr0 * L_ + ((vc0 ^ (vr0 & 7)) * 8);
  const bf16* vp1 = vb + (size_t)vr1 * L_ + ((vc0 ^ (vr1 & 7)) * 8);

  const int ntiles = ((qt >> 3) + 1) * 4;
  // prologue stage tile 0 -> buf 0 (flies while we do Q norm math)
  gload16(kp0, &sK[0][tid * 8]);
  gload16(kp1, &sK[0][(512 + tid) * 8]);
  gload16(vp0, &sV[0][tid * 8]);
  gload16(vp1, &sV[0][(512 + tid) * 8]);

  // Q norm math (overlaps staging)
  ss += __shfl_xor(ss, 16);
  ss += __shfl_xor(ss, 32);
  const float rr = rsqrtf(ss * (1.0f / 128.0f) + 1e-6f);
  bf16x8 qf[4];
#pragma unroll
  for (int c = 0; c < 2; ++c)
#pragma unroll
    for (int j = 0; j < 8; ++j) {
      int i = c * 32 + kk + j;
      float n1 = t[c][j] * rr * qnw[i];
      float n2 = t[c + 2][j] * rr * qnw[i + 64];
      float cs = cosb[qrow * 64 + i], sn = sinb[qrow * 64 + i];
      qf[c][j] = (bf16)(n1 * cs - n2 * sn);
      qf[c + 2][j] = (bf16)(n2 * cs + n1 * sn);
    }

  bf16* myP = sP + wid * 16 * 64;
  f32x4 acc[8] = {};
  float mrow[4], lrow[4];
#pragma unroll
  for (int r = 0; r < 4; ++r) { mrow[r] = -1e30f; lrow[r] = 0.f; }
  constexpr float SCL = 0.12752650038632816f;  // 128^-0.5 * log2(e)

  __syncthreads();  // tile 0 staged (compiler drains vmcnt before barrier)

  for (int kt = 0; kt < ntiles; ++kt) {
    const int cur = kt & 1;
    if (kt + 1 < ntiles) {  // stage next tile into other buffer (async)
      const int p = cur ^ 1;
      gload16(kp0 + (size_t)(kt + 1) * 64 * D_, &sK[p][tid * 8]);
      gload16(kp1 + (size_t)(kt + 1) * 64 * D_, &sK[p][(512 + tid) * 8]);
      gload16(vp0 + (kt + 1) * 64, &sV[p][tid * 8]);
      gload16(vp1 + (kt + 1) * 64, &sV[p][(512 + tid) * 8]);
    }
    const char* cK = (const char*)&sK[cur][0];
    const char* cV = (const char*)&sV[cur][0];
    // --- QK^T ---
    f32x4 s[4];
#pragma unroll
    for (int n = 0; n < 4; ++n) {
      f32x4 st = {};
#pragma unroll
      for (int c = 0; c < 4; ++c) {
        int byte = (n * 16 + l15) * 256 + ((((c << 2) + g4) ^ (l15 & 7)) << 4);
        bf16x8 kf = *reinterpret_cast<const bf16x8*>(cK + byte);
        st = __builtin_amdgcn_mfma_f32_16x16x32_bf16(qf[c], kf, st, 0, 0, 0);
      }
      s[n] = st * SCL;
    }
    // --- online softmax (log2 domain) ---
    float pm[4], rsum[4];
#pragma unroll
    for (int r = 0; r < 4; ++r)
      pm[r] = fmaxf(fmaxf(s[0][r], s[1][r]), fmaxf(s[2][r], s[3][r]));
#pragma unroll
    for (int off = 1; off < 16; off <<= 1)
#pragma unroll
      for (int r = 0; r < 4; ++r) pm[r] = fmaxf(pm[r], __shfl_xor(pm[r], off));
#pragma unroll
    for (int r = 0; r < 4; ++r) {
      float mnew = fmaxf(mrow[r], pm[r]);
      float resc = exp2f(mrow[r] - mnew);
      mrow[r] = mnew;
      lrow[r] *= resc;
#pragma unroll
      for (int f = 0; f < 8; ++f) acc[f][r] *= resc;
      float rs = 0.f;
#pragma unroll
      for (int n = 0; n < 4; ++n) {
        float p = exp2f(s[n][r] - mnew);
        s[n][r] = p;
        rs += p;
      }
      rsum[r] = rs;
    }
#pragma unroll
    for (int off = 1; off < 16; off <<= 1)
#pragma unroll
      for (int r = 0; r < 4; ++r) rsum[r] += __shfl_xor(rsum[r], off);
#pragma unroll
    for (int r = 0; r < 4; ++r) lrow[r] += rsum[r];
    // --- P -> LDS (wave-private, XOR-swizzled, no barrier) ---
#pragma unroll
    for (int n = 0; n < 4; ++n)
#pragma unroll
      for (int r = 0; r < 4; ++r) {
        int pr = (g4 << 2) + r;
        int byte = pr * 128 + (((n * 32) + (l15 * 2)) ^ ((pr & 7) << 4));
        *reinterpret_cast<bf16*>((char*)myP + byte) = (bf16)s[n][r];
      }
    bf16x8 pf0 = *reinterpret_cast<const bf16x8*>(
        (char*)myP + l15 * 128 + ((g4 ^ (l15 & 7)) << 4));
    bf16x8 pf1 = *reinterpret_cast<const bf16x8*>(
        (char*)myP + l15 * 128 + (((4 + g4) ^ (l15 & 7)) << 4));
    // --- PV ---
#pragma unroll
    for (int f = 0; f < 8; ++f) {
      int d = f * 16 + l15;
      bf16x8 vf0 = *reinterpret_cast<const bf16x8*>(
          cV + d * 128 + ((g4 ^ (l15 & 7)) << 4));
      acc[f] = __builtin_amdgcn_mfma_f32_16x16x32_bf16(pf0, vf0, acc[f], 0, 0, 0);
      bf16x8 vf1 = *reinterpret_cast<const bf16x8*>(
          cV + d * 128 + (((4 + g4) ^ (l15 & 7)) << 4));
      acc[f] = __builtin_amdgcn_mfma_f32_16x16x32_bf16(pf1, vf1, acc[f], 0, 0, 0);
    }
    __syncthreads();  // drains this iter's prefetch (late) + releases buffers
  }
  // --- epilogue ---
#pragma unroll
  for (int f = 0; f < 8; ++f)
#pragma unroll
    for (int r = 0; r < 4; ++r) {
      int row = qrow0 + g4 * 4 + r;
      AO[((size_t)(b * L_ + row) * H_ + h) * D_ + f * 16 + l15] = (bf16)(acc[f][r] / lrow[r]);
    }
}

// ---------------- launch ----------------
extern "C" void kernel_launch(void* const* d_in, const int* in_sizes, int n_in,
                              void* d_out, int out_size, void* d_ws, size_t ws_size,
                              hipStream_t stream) {
  const float* x = (const float*)d_in[0];
  const float* Wq = (const float*)d_in[1];
  const float* Wk = (const float*)d_in[2];
  const float* Wv = (const float*)d_in[3];
  const float* Wo = (const float*)d_in[4];
  const float* qnw = (const float*)d_in[5];
  const float* knw = (const float*)d_in[6];
  const float* rc = (const float*)d_in[7];
  const float* rs = (const float*)d_in[8];
  float* out = (float*)d_out;

  char* ws = (char*)d_ws;
  bf16* xb = (bf16*)ws;    ws += (size_t)TOK_ * C_ * 2;
  bf16* wqb = (bf16*)ws;   ws += (size_t)(H_ * D_) * C_ * 2;   // wq/wk/wv contiguous!
  bf16* wkb = (bf16*)ws;   ws += (size_t)(HKV_ * D_) * C_ * 2;
  bf16* wvb = (bf16*)ws;   ws += (size_t)(HKV_ * D_) * C_ * 2;
  bf16* wob = (bf16*)ws;   ws += (size_t)C_ * (H_ * D_) * 2;
  bf16* qkv = (bf16*)ws;   ws += (size_t)TOK_ * NQKV_ * 2;
  bf16* Kb = (bf16*)ws;    ws += (size_t)TOK_ * HKV_ * D_ * 2;
  bf16* Vtb = (bf16*)ws;   ws += (size_t)TOK_ * HKV_ * D_ * 2;
  bf16* AOb = xb;  // alias: xb dead after projection GEMM

  auto cvt = [&](const float* src, bf16* dst, size_t n) {
    int n4 = (int)(n / 4);
    int grid = (n4 + 255) / 256;
    if (grid > 4096) grid = 4096;
    cvt_bf16<<<grid, 256, 0, stream>>>(src, dst, n4);
  };
  cvt(x, xb, (size_t)TOK_ * C_);
  cvt(Wq, wqb, (size_t)H_ * D_ * C_);
  cvt(Wk, wkb, (size_t)HKV_ * D_ * C_);
  cvt(Wv, wvb, (size_t)HKV_ * D_ * C_);
  cvt(Wo, wob, (size_t)C_ * H_ * D_);

  // fused QKV projection: N = 3072 (wq,wk,wv rows contiguous)
  gemm_bt<false><<<dim3(TOK_ / 128, NQKV_ / 128), 256, 0, stream>>>(
      xb, wqb, qkv, TOK_, NQKV_, C_);

  k_norm_rope<<<(TOK_ * HKV_) / 4, 256, 0, stream>>>(qkv, knw, rc, rs, Kb);
  v_transpose<<<dim3(L_ / 64, B_ * HKV_), 256, 0, stream>>>(qkv, Vtb);

  attn_fused<<<512, 512, 0, stream>>>(qkv, Kb, Vtb, qnw, rc, rs, AOb);

  gemm_bt<true><<<dim3(TOK_ / 128, C_ / 128), 256, 0, stream>>>(
      AOb, wob, out, TOK_, C_, H_ * D_);
}

// Round 4
// 236.483 us; speedup vs baseline: 3.8372x; 1.1176x over previous
//
#include <hip/hip_runtime.h>

#define B_ 2
#define L_ 2048
#define C_ 2048
#define H_ 16
#define HKV_ 4
#define D_ 128
#define G_ (H_ / HKV_)
#define TOK_ (B_ * L_)
#define NQKV_ 3072  // H*D + 2*HKV*D

typedef __bf16 bf16;
typedef __bf16 bf16x4 __attribute__((ext_vector_type(4)));
typedef __bf16 bf16x8 __attribute__((ext_vector_type(8)));
typedef float f32x4 __attribute__((ext_vector_type(4)));

__device__ inline void gload16(const void* g, void* l) {
  __builtin_amdgcn_global_load_lds(
      (const __attribute__((address_space(1))) void*)g,
      (__attribute__((address_space(3))) void*)l, 16, 0, 0);
}

// ---------------- fp32 -> bf16 conversion ----------------
__global__ void cvt_bf16(const float* __restrict__ in, bf16* __restrict__ out, int n4) {
  int stride = gridDim.x * blockDim.x;
  for (int j = blockIdx.x * blockDim.x + threadIdx.x; j < n4; j += stride) {
    float4 v = reinterpret_cast<const float4*>(in)[j];
    bf16x4 o = {(bf16)v.x, (bf16)v.y, (bf16)v.z, (bf16)v.w};
    reinterpret_cast<bf16x4*>(out)[j] = o;
  }
}

// ---------------- GEMM: C[M,N] = A[M,K] @ B[N,K]^T (bf16 in, f32 acc) ------
// 128x128 tile, BK=32, 4 waves, global_load_lds staging (m97 structure).
template <bool OUT_F32>
__global__ __launch_bounds__(256) void gemm_bt(
    const bf16* __restrict__ A, const bf16* __restrict__ Bm,
    void* __restrict__ Cm, int M, int N, int K) {
  __shared__ __align__(16) bf16 sA[128 * 32];
  __shared__ __align__(16) bf16 sB[128 * 32];
  const int tid = threadIdx.x;
  const int row0 = blockIdx.x * 128, col0 = blockIdx.y * 128;
  const int wid = tid >> 6, lane = tid & 63;
  const int wr = wid >> 1, wc = wid & 1;
  const int l15 = lane & 15, kk = (lane >> 4) * 8;
  f32x4 acc[4][4] = {};
  const int nk = K / 32;
  const int f0 = tid;
  const int r0 = f0 >> 2, c0 = f0 & 3;
  const int f1 = 256 + tid;
  const int r1 = f1 >> 2, c1 = f1 & 3;
  const int ldsA0 = (wid * 64) * 8, ldsA1 = (256 + wid * 64) * 8;
  for (int kt = 0; kt < nk; ++kt) {
    __syncthreads();
    gload16(A + (size_t)(row0 + r0) * K + kt * 32 + c0 * 8, sA + ldsA0);
    gload16(A + (size_t)(row0 + r1) * K + kt * 32 + c1 * 8, sA + ldsA1);
    gload16(Bm + (size_t)(col0 + r0) * K + kt * 32 + c0 * 8, sB + ldsA0);
    gload16(Bm + (size_t)(col0 + r1) * K + kt * 32 + c1 * 8, sB + ldsA1);
    __syncthreads();
    bf16x8 af[4], bfr[4];
#pragma unroll
    for (int m = 0; m < 4; ++m)
      af[m] = *reinterpret_cast<const bf16x8*>(sA + (wr * 64 + m * 16 + l15) * 32 + kk);
#pragma unroll
    for (int n = 0; n < 4; ++n)
      bfr[n] = *reinterpret_cast<const bf16x8*>(sB + (wc * 64 + n * 16 + l15) * 32 + kk);
#pragma unroll
    for (int m = 0; m < 4; ++m)
#pragma unroll
      for (int n = 0; n < 4; ++n)
        acc[m][n] = __builtin_amdgcn_mfma_f32_16x16x32_bf16(af[m], bfr[n], acc[m][n], 0, 0, 0);
  }
#pragma unroll
  for (int m = 0; m < 4; ++m)
#pragma unroll
    for (int n = 0; n < 4; ++n)
#pragma unroll
      for (int r = 0; r < 4; ++r) {
        int row = row0 + wr * 64 + m * 16 + (lane >> 4) * 4 + r;
        int col = col0 + wc * 64 + n * 16 + l15;
        if constexpr (OUT_F32)
          reinterpret_cast<float*>(Cm)[(size_t)row * N + col] = acc[m][n][r];
        else
          reinterpret_cast<bf16*>(Cm)[(size_t)row * N + col] = (bf16)acc[m][n][r];
      }
}

// ---------------- RMSNorm + RoPE for K, relayout to (B, HKV, L, D) ---------
__global__ void k_norm_rope(const bf16* __restrict__ proj,  // (TOK, NQKV)
                            const float* __restrict__ normw,
                            const float* __restrict__ cosb,  // (L, 64)
                            const float* __restrict__ sinb,
                            bf16* __restrict__ out) {  // (B, HKV, L, D)
  int wid = (blockIdx.x * blockDim.x + threadIdx.x) >> 6;
  int lane = threadIdx.x & 63;
  int head = wid & 3, tok = wid >> 2;
  int b = tok / L_, l = tok % L_;
  const bf16* p = proj + (size_t)tok * NQKV_ + H_ * D_ + head * D_;
  float t1 = (float)p[lane];
  float t2 = (float)p[lane + 64];
  float ss = t1 * t1 + t2 * t2;
#pragma unroll
  for (int off = 32; off; off >>= 1) ss += __shfl_xor(ss, off);
  float r = rsqrtf(ss * (1.0f / 128.0f) + 1e-6f);
  float n1 = t1 * r * normw[lane];
  float n2 = t2 * r * normw[lane + 64];
  float c = cosb[l * 64 + lane], s = sinb[l * 64 + lane];
  bf16* q = out + (((size_t)b * HKV_ + head) * L_ + l) * D_;
  q[lane] = (bf16)(n1 * c - n2 * s);
  q[lane + 64] = (bf16)(n2 * c + n1 * s);
}

// ---------------- V transpose (LDS-tiled): (TOK,NQKV col 2560+) -> (B,HKV,D,L)
__global__ __launch_bounds__(256) void v_transpose(const bf16* __restrict__ proj,
                                                   bf16* __restrict__ vt) {
  __shared__ __align__(16) bf16 sT[64 * 136];
  const int t = threadIdx.x;
  const int l0 = blockIdx.x * 64;
  const int bk = blockIdx.y;  // b*HKV+h
  const bf16* src = proj + (size_t)((bk >> 2) * L_ + l0) * NQKV_ + (H_ + HKV_) * D_ + (bk & 3) * D_;
#pragma unroll
  for (int c = 0; c < 4; ++c) {
    int idx = c * 256 + t;
    int l = idx >> 4, dc = idx & 15;
    bf16x8 v = *reinterpret_cast<const bf16x8*>(src + (size_t)l * NQKV_ + dc * 8);
    *reinterpret_cast<bf16x8*>((char*)sT + l * 272 + ((dc ^ (l >> 3)) << 4)) = v;
  }
  __syncthreads();
  bf16* dst = vt + (size_t)bk * D_ * L_ + l0;
#pragma unroll
  for (int c = 0; c < 4; ++c) {
    int idx = c * 256 + t;
    int d = idx >> 3, lg = idx & 7;
    bf16x8 o;
#pragma unroll
    for (int j = 0; j < 8; ++j) {
      int l = lg * 8 + j;
      o[j] = *reinterpret_cast<const bf16*>((char*)sT + l * 272 + (((d >> 3) ^ lg) << 4) + (d & 7) * 2);
    }
    *reinterpret_cast<bf16x8*>(dst + (size_t)d * L_ + lg * 8) = o;
  }
}

// ---------------- Fused flash attention, block-causal, GQA -----------------
// 512 thr = 8 waves = 4 heads x 2 q-subtiles(16 rows) over 32 q rows.
// Double-buffered K/V (64-key tiles) via global_load_lds, XOR-swizzled.
// Defer-max online softmax (THR=8), deferred row-sum reduce (epilogue only).
__global__ __launch_bounds__(512, 4) void attn_fused(
    const bf16* __restrict__ QKV,  // (TOK, NQKV) raw projections
    const bf16* __restrict__ Kn,   // (B,HKV,L,D) normed+roped
    const bf16* __restrict__ Vt,   // (B,HKV,D,L)
    const float* __restrict__ qnw,
    const float* __restrict__ cosb, const float* __restrict__ sinb,
    bf16* __restrict__ AO) {  // (B,L,H,D)
  __shared__ __align__(16) bf16 sK[2][64 * 128];
  __shared__ __align__(16) bf16 sV[2][64 * 128];
  __shared__ __align__(16) bf16 sP[8 * 16 * 64];
  const int tid = threadIdx.x;
  const int wid = tid >> 6, lane = tid & 63;
  const int bid = blockIdx.x;
  const int bk = bid & 7;          // same-bk blocks land on same XCD (bid%8)
  const int qt = 63 - (bid >> 3);  // longest blocks first
  const int b = bk >> 2;
  const int hl = wid & 3, qs = wid >> 2;
  const int h = (bk & 3) * G_ + hl;
  const int qrow0 = qt * 32 + qs * 16;
  const int l15 = lane & 15, g4 = lane >> 4, kk = g4 * 8;

  // ---- fused Q: load + RMSNorm + RoPE (row = qrow0 + l15) ----
  const int qrow = qrow0 + l15;
  const bf16* qsrc = QKV + (size_t)(b * L_ + qrow) * NQKV_ + h * D_;
  float t[4][8];
  float ss = 0.f;
#pragma unroll
  for (int c = 0; c < 4; ++c) {
    bf16x8 v = *reinterpret_cast<const bf16x8*>(qsrc + c * 32 + kk);
#pragma unroll
    for (int j = 0; j < 8; ++j) { t[c][j] = (float)v[j]; ss += t[c][j] * t[c][j]; }
  }

  // staging coordinates (pre-swizzled global sources, linear LDS dest)
  const int kr0 = tid >> 4, kc0 = tid & 15;
  const int kr1 = 32 + kr0;
  const int vr0 = tid >> 3, vc0 = tid & 7;
  const int vr1 = 64 + vr0;
  const bf16* kb = Kn + (size_t)bk * L_ * D_;
  const bf16* vb = Vt + (size_t)bk * D_ * (size_t)L_;
  const bf16* kp0 = kb + (size_t)kr0 * D_ + ((kc0 ^ (kr0 & 7)) * 8);
  const bf16* kp1 = kb + (size_t)kr1 * D_ + ((kc0 ^ (kr1 & 7)) * 8);
  const bf16* vp0 = vb + (size_t)vr0 * L_ + ((vc0 ^ (vr0 & 7)) * 8);
  const bf16* vp1 = vb + (size_t)vr1 * L_ + ((vc0 ^ (vr1 & 7)) * 8);

  const int ntiles = ((qt >> 3) + 1) * 4;  // multiple of 4 -> kt-unroll-2 safe
  // prologue stage tile 0 -> buf 0 (flies while we do Q norm math)
  gload16(kp0, &sK[0][tid * 8]);
  gload16(kp1, &sK[0][(512 + tid) * 8]);
  gload16(vp0, &sV[0][tid * 8]);
  gload16(vp1, &sV[0][(512 + tid) * 8]);

  // Q norm math (overlaps staging); fold scale*log2e into Q fragments
  constexpr float SCL = 0.12752650038632816f;  // 128^-0.5 * log2(e)
  ss += __shfl_xor(ss, 16);
  ss += __shfl_xor(ss, 32);
  const float rr = rsqrtf(ss * (1.0f / 128.0f) + 1e-6f);
  bf16x8 qf[4];
#pragma unroll
  for (int c = 0; c < 2; ++c)
#pragma unroll
    for (int j = 0; j < 8; ++j) {
      int i = c * 32 + kk + j;
      float n1 = t[c][j] * rr * qnw[i];
      float n2 = t[c + 2][j] * rr * qnw[i + 64];
      float cs = cosb[qrow * 64 + i], sn = sinb[qrow * 64 + i];
      qf[c][j] = (bf16)((n1 * cs - n2 * sn) * SCL);
      qf[c + 2][j] = (bf16)((n2 * cs + n1 * sn) * SCL);
    }

  bf16* myP = sP + wid * 16 * 64;
  f32x4 acc[8] = {};
  float mref[4], lpart[4];
#pragma unroll
  for (int r = 0; r < 4; ++r) { mref[r] = -1e30f; lpart[r] = 0.f; }

  __syncthreads();  // tile 0 staged (compiler drains vmcnt before barrier)

  // one kv-tile step; buffer choice is compile-time via manual unroll-2
  auto tile_step = [&](const bf16* sKc, const bf16* sVc, bf16* sKn_, bf16* sVn_,
                       int ktNext, bool doPref) {
    if (doPref) {
      gload16(kp0 + (size_t)ktNext * 64 * D_, &sKn_[tid * 8]);
      gload16(kp1 + (size_t)ktNext * 64 * D_, &sKn_[(512 + tid) * 8]);
      gload16(vp0 + ktNext * 64, &sVn_[tid * 8]);
      gload16(vp1 + ktNext * 64, &sVn_[(512 + tid) * 8]);
    }
    const char* cK = (const char*)sKc;
    const char* cV = (const char*)sVc;
    // --- QK^T (pre-scaled, log2 domain) ---
    f32x4 s[4];
#pragma unroll
    for (int n = 0; n < 4; ++n) {
      f32x4 st = {};
#pragma unroll
      for (int c = 0; c < 4; ++c) {
        int byte = (n * 16 + l15) * 256 + ((((c << 2) + g4) ^ (l15 & 7)) << 4);
        bf16x8 kf = *reinterpret_cast<const bf16x8*>(cK + byte);
        st = __builtin_amdgcn_mfma_f32_16x16x32_bf16(qf[c], kf, st, 0, 0, 0);
      }
      s[n] = st;
    }
    // --- defer-max online softmax ---
    float pm[4];
#pragma unroll
    for (int r = 0; r < 4; ++r)
      pm[r] = fmaxf(fmaxf(s[0][r], s[1][r]), fmaxf(s[2][r], s[3][r]));
    int ok = (pm[0] <= mref[0] + 8.f) & (pm[1] <= mref[1] + 8.f) &
             (pm[2] <= mref[2] + 8.f) & (pm[3] <= mref[3] + 8.f);
    if (!__all(ok)) {  // rare: true max grew -> reduce, rescale
#pragma unroll
      for (int off = 1; off < 16; off <<= 1)
#pragma unroll
        for (int r = 0; r < 4; ++r) pm[r] = fmaxf(pm[r], __shfl_xor(pm[r], off));
#pragma unroll
      for (int r = 0; r < 4; ++r) {
        float mnew = fmaxf(mref[r], pm[r]);
        float resc = exp2f(mref[r] - mnew);
        mref[r] = mnew;
        lpart[r] *= resc;
#pragma unroll
        for (int f = 0; f < 8; ++f) acc[f][r] *= resc;
      }
    }
#pragma unroll
    for (int r = 0; r < 4; ++r) {
      float lp = lpart[r];
#pragma unroll
      for (int n = 0; n < 4; ++n) {
        float p = exp2f(s[n][r] - mref[r]);
        s[n][r] = p;
        lp += p;
      }
      lpart[r] = lp;
    }
    // --- P -> LDS (wave-private, XOR-swizzled, no barrier) ---
#pragma unroll
    for (int n = 0; n < 4; ++n)
#pragma unroll
      for (int r = 0; r < 4; ++r) {
        int pr = (g4 << 2) + r;
        int byte = pr * 128 + (((n * 32) + (l15 * 2)) ^ ((pr & 7) << 4));
        *reinterpret_cast<bf16*>((char*)myP + byte) = (bf16)s[n][r];
      }
    bf16x8 pf0 = *reinterpret_cast<const bf16x8*>(
        (char*)myP + l15 * 128 + ((g4 ^ (l15 & 7)) << 4));
    bf16x8 pf1 = *reinterpret_cast<const bf16x8*>(
        (char*)myP + l15 * 128 + (((4 + g4) ^ (l15 & 7)) << 4));
    // --- PV ---
#pragma unroll
    for (int f = 0; f < 8; ++f) {
      int d = f * 16 + l15;
      bf16x8 vf0 = *reinterpret_cast<const bf16x8*>(
          cV + d * 128 + ((g4 ^ (l15 & 7)) << 4));
      acc[f] = __builtin_amdgcn_mfma_f32_16x16x32_bf16(pf0, vf0, acc[f], 0, 0, 0);
      bf16x8 vf1 = *reinterpret_cast<const bf16x8*>(
          cV + d * 128 + (((4 + g4) ^ (l15 & 7)) << 4));
      acc[f] = __builtin_amdgcn_mfma_f32_16x16x32_bf16(pf1, vf1, acc[f], 0, 0, 0);
    }
    __syncthreads();  // drains this iter's prefetch (late) + releases buffers
  };

  for (int kt = 0; kt < ntiles; kt += 2) {
    tile_step(sK[0], sV[0], sK[1], sV[1], kt + 1, true);
    tile_step(sK[1], sV[1], sK[0], sV[0], kt + 2, kt + 2 < ntiles);
  }

  // --- epilogue: single row-sum reduce, then normalize ---
#pragma unroll
  for (int off = 1; off < 16; off <<= 1)
#pragma unroll
    for (int r = 0; r < 4; ++r) lpart[r] += __shfl_xor(lpart[r], off);
  float rinv[4];
#pragma unroll
  for (int r = 0; r < 4; ++r) rinv[r] = 1.f / lpart[r];
#pragma unroll
  for (int f = 0; f < 8; ++f)
#pragma unroll
    for (int r = 0; r < 4; ++r) {
      int row = qrow0 + g4 * 4 + r;
      AO[((size_t)(b * L_ + row) * H_ + h) * D_ + f * 16 + l15] =
          (bf16)(acc[f][r] * rinv[r]);
    }
}

// ---------------- launch ----------------
extern "C" void kernel_launch(void* const* d_in, const int* in_sizes, int n_in,
                              void* d_out, int out_size, void* d_ws, size_t ws_size,
                              hipStream_t stream) {
  const float* x = (const float*)d_in[0];
  const float* Wq = (const float*)d_in[1];
  const float* Wk = (const float*)d_in[2];
  const float* Wv = (const float*)d_in[3];
  const float* Wo = (const float*)d_in[4];
  const float* qnw = (const float*)d_in[5];
  const float* knw = (const float*)d_in[6];
  const float* rc = (const float*)d_in[7];
  const float* rs = (const float*)d_in[8];
  float* out = (float*)d_out;

  char* ws = (char*)d_ws;
  bf16* xb = (bf16*)ws;    ws += (size_t)TOK_ * C_ * 2;
  bf16* wqb = (bf16*)ws;   ws += (size_t)(H_ * D_) * C_ * 2;   // wq/wk/wv contiguous!
  bf16* wkb = (bf16*)ws;   ws += (size_t)(HKV_ * D_) * C_ * 2;
  bf16* wvb = (bf16*)ws;   ws += (size_t)(HKV_ * D_) * C_ * 2;
  bf16* wob = (bf16*)ws;   ws += (size_t)C_ * (H_ * D_) * 2;
  bf16* qkv = (bf16*)ws;   ws += (size_t)TOK_ * NQKV_ * 2;
  bf16* Kb = (bf16*)ws;    ws += (size_t)TOK_ * HKV_ * D_ * 2;
  bf16* Vtb = (bf16*)ws;   ws += (size_t)TOK_ * HKV_ * D_ * 2;
  bf16* AOb = xb;  // alias: xb dead after projection GEMM

  auto cvt = [&](const float* src, bf16* dst, size_t n) {
    int n4 = (int)(n / 4);
    int grid = (n4 + 255) / 256;
    if (grid > 4096) grid = 4096;
    cvt_bf16<<<grid, 256, 0, stream>>>(src, dst, n4);
  };
  cvt(x, xb, (size_t)TOK_ * C_);
  cvt(Wq, wqb, (size_t)H_ * D_ * C_);
  cvt(Wk, wkb, (size_t)HKV_ * D_ * C_);
  cvt(Wv, wvb, (size_t)HKV_ * D_ * C_);
  cvt(Wo, wob, (size_t)C_ * H_ * D_);

  // fused QKV projection: N = 3072 (wq,wk,wv rows contiguous)
  gemm_bt<false><<<dim3(TOK_ / 128, NQKV_ / 128), 256, 0, stream>>>(
      xb, wqb, qkv, TOK_, NQKV_, C_);

  k_norm_rope<<<(TOK_ * HKV_) / 4, 256, 0, stream>>>(qkv, knw, rc, rs, Kb);
  v_transpose<<<dim3(L_ / 64, B_ * HKV_), 256, 0, stream>>>(qkv, Vtb);

  attn_fused<<<512, 512, 0, stream>>>(qkv, Kb, Vtb, qnw, rc, rs, AOb);

  gemm_bt<true><<<dim3(TOK_ / 128, C_ / 128), 256, 0, stream>>>(
      AOb, wob, out, TOK_, C_, H_ * D_);
}

// Round 5
// 218.476 us; speedup vs baseline: 4.1535x; 1.0824x over previous
//
#include <hip/hip_runtime.h>

#define B_ 2
#define L_ 2048
#define C_ 2048
#define H_ 16
#define HKV_ 4
#define D_ 128
#define G_ (H_ / HKV_)
#define TOK_ (B_ * L_)
#define NQKV_ 3072  // H*D + 2*HKV*D

typedef __bf16 bf16;
typedef __bf16 bf16x4 __attribute__((ext_vector_type(4)));
typedef __bf16 bf16x8 __attribute__((ext_vector_type(8)));
typedef float f32x4 __attribute__((ext_vector_type(4)));

__device__ inline void gload16(const void* g, void* l) {
  __builtin_amdgcn_global_load_lds(
      (const __attribute__((address_space(1))) void*)g,
      (__attribute__((address_space(3))) void*)l, 16, 0, 0);
}

// ---------------- fp32 -> bf16 conversion ----------------
__global__ void cvt_bf16(const float* __restrict__ in, bf16* __restrict__ out, int n4) {
  int stride = gridDim.x * blockDim.x;
  for (int j = blockIdx.x * blockDim.x + threadIdx.x; j < n4; j += stride) {
    float4 v = reinterpret_cast<const float4*>(in)[j];
    bf16x4 o = {(bf16)v.x, (bf16)v.y, (bf16)v.z, (bf16)v.w};
    reinterpret_cast<bf16x4*>(out)[j] = o;
  }
}

// ---------------- GEMM: C[M,N] = A[M,K] @ B[N,K]^T (bf16 in, f32 acc) ------
// 128x128 tile, BK=32, 4 waves, global_load_lds staging (m97 structure).
template <bool OUT_F32>
__global__ __launch_bounds__(256) void gemm_bt(
    const bf16* __restrict__ A, const bf16* __restrict__ Bm,
    void* __restrict__ Cm, int M, int N, int K) {
  __shared__ __align__(16) bf16 sA[128 * 32];
  __shared__ __align__(16) bf16 sB[128 * 32];
  const int tid = threadIdx.x;
  const int row0 = blockIdx.x * 128, col0 = blockIdx.y * 128;
  const int wid = tid >> 6, lane = tid & 63;
  const int wr = wid >> 1, wc = wid & 1;
  const int l15 = lane & 15, kk = (lane >> 4) * 8;
  f32x4 acc[4][4] = {};
  const int nk = K / 32;
  const int f0 = tid;
  const int r0 = f0 >> 2, c0 = f0 & 3;
  const int f1 = 256 + tid;
  const int r1 = f1 >> 2, c1 = f1 & 3;
  const int ldsA0 = (wid * 64) * 8, ldsA1 = (256 + wid * 64) * 8;
  for (int kt = 0; kt < nk; ++kt) {
    __syncthreads();
    gload16(A + (size_t)(row0 + r0) * K + kt * 32 + c0 * 8, sA + ldsA0);
    gload16(A + (size_t)(row0 + r1) * K + kt * 32 + c1 * 8, sA + ldsA1);
    gload16(Bm + (size_t)(col0 + r0) * K + kt * 32 + c0 * 8, sB + ldsA0);
    gload16(Bm + (size_t)(col0 + r1) * K + kt * 32 + c1 * 8, sB + ldsA1);
    __syncthreads();
    bf16x8 af[4], bfr[4];
#pragma unroll
    for (int m = 0; m < 4; ++m)
      af[m] = *reinterpret_cast<const bf16x8*>(sA + (wr * 64 + m * 16 + l15) * 32 + kk);
#pragma unroll
    for (int n = 0; n < 4; ++n)
      bfr[n] = *reinterpret_cast<const bf16x8*>(sB + (wc * 64 + n * 16 + l15) * 32 + kk);
#pragma unroll
    for (int m = 0; m < 4; ++m)
#pragma unroll
      for (int n = 0; n < 4; ++n)
        acc[m][n] = __builtin_amdgcn_mfma_f32_16x16x32_bf16(af[m], bfr[n], acc[m][n], 0, 0, 0);
  }
#pragma unroll
  for (int m = 0; m < 4; ++m)
#pragma unroll
    for (int n = 0; n < 4; ++n)
#pragma unroll
      for (int r = 0; r < 4; ++r) {
        int row = row0 + wr * 64 + m * 16 + (lane >> 4) * 4 + r;
        int col = col0 + wc * 64 + n * 16 + l15;
        if constexpr (OUT_F32)
          reinterpret_cast<float*>(Cm)[(size_t)row * N + col] = acc[m][n][r];
        else
          reinterpret_cast<bf16*>(Cm)[(size_t)row * N + col] = (bf16)acc[m][n][r];
      }
}

// ---------------- RMSNorm + RoPE for K, relayout to (B, HKV, L, D) ---------
__global__ void k_norm_rope(const bf16* __restrict__ proj,  // (TOK, NQKV)
                            const float* __restrict__ normw,
                            const float* __restrict__ cosb,  // (L, 64)
                            const float* __restrict__ sinb,
                            bf16* __restrict__ out) {  // (B, HKV, L, D)
  int wid = (blockIdx.x * blockDim.x + threadIdx.x) >> 6;
  int lane = threadIdx.x & 63;
  int head = wid & 3, tok = wid >> 2;
  int b = tok / L_, l = tok % L_;
  const bf16* p = proj + (size_t)tok * NQKV_ + H_ * D_ + head * D_;
  float t1 = (float)p[lane];
  float t2 = (float)p[lane + 64];
  float ss = t1 * t1 + t2 * t2;
#pragma unroll
  for (int off = 32; off; off >>= 1) ss += __shfl_xor(ss, off);
  float r = rsqrtf(ss * (1.0f / 128.0f) + 1e-6f);
  float n1 = t1 * r * normw[lane];
  float n2 = t2 * r * normw[lane + 64];
  float c = cosb[l * 64 + lane], s = sinb[l * 64 + lane];
  bf16* q = out + (((size_t)b * HKV_ + head) * L_ + l) * D_;
  q[lane] = (bf16)(n1 * c - n2 * s);
  q[lane + 64] = (bf16)(n2 * c + n1 * s);
}

// ---------------- V transpose (LDS-tiled): (TOK,NQKV col 2560+) -> (B,HKV,D,L)
__global__ __launch_bounds__(256) void v_transpose(const bf16* __restrict__ proj,
                                                   bf16* __restrict__ vt) {
  __shared__ __align__(16) bf16 sT[64 * 136];
  const int t = threadIdx.x;
  const int l0 = blockIdx.x * 64;
  const int bk = blockIdx.y;  // b*HKV+h
  const bf16* src = proj + (size_t)((bk >> 2) * L_ + l0) * NQKV_ + (H_ + HKV_) * D_ + (bk & 3) * D_;
#pragma unroll
  for (int c = 0; c < 4; ++c) {
    int idx = c * 256 + t;
    int l = idx >> 4, dc = idx & 15;
    bf16x8 v = *reinterpret_cast<const bf16x8*>(src + (size_t)l * NQKV_ + dc * 8);
    *reinterpret_cast<bf16x8*>((char*)sT + l * 272 + ((dc ^ (l >> 3)) << 4)) = v;
  }
  __syncthreads();
  bf16* dst = vt + (size_t)bk * D_ * L_ + l0;
#pragma unroll
  for (int c = 0; c < 4; ++c) {
    int idx = c * 256 + t;
    int d = idx >> 3, lg = idx & 7;
    bf16x8 o;
#pragma unroll
    for (int j = 0; j < 8; ++j) {
      int l = lg * 8 + j;
      o[j] = *reinterpret_cast<const bf16*>((char*)sT + l * 272 + (((d >> 3) ^ lg) << 4) + (d & 7) * 2);
    }
    *reinterpret_cast<bf16x8*>(dst + (size_t)d * L_ + lg * 8) = o;
  }
}

// ---------------- Fused flash attention, block-causal, GQA -----------------
// 512 thr = 8 waves = 4 heads x 2 q-subtiles(16 rows) over 32 q rows.
// Swapped QK^T (S^T = K*Q^T): each lane owns one q-row -> scalar softmax
// state, 4x b64 P-writes, packed epilogue. Double-buffered K/V staging.
__global__ __launch_bounds__(512, 4) void attn_fused(
    const bf16* __restrict__ QKV,  // (TOK, NQKV) raw projections
    const bf16* __restrict__ Kn,   // (B,HKV,L,D) normed+roped
    const bf16* __restrict__ Vt,   // (B,HKV,D,L)
    const float* __restrict__ qnw,
    const float* __restrict__ cosb, const float* __restrict__ sinb,
    bf16* __restrict__ AO) {  // (B,L,H,D)
  __shared__ __align__(16) bf16 sK[2][64 * 128];
  __shared__ __align__(16) bf16 sV[2][64 * 128];
  __shared__ __align__(16) bf16 sP[8 * 16 * 64];
  const int tid = threadIdx.x;
  const int wid = tid >> 6, lane = tid & 63;
  const int bid = blockIdx.x;
  const int bk = bid & 7;  // same-bk blocks land on same XCD (bid%8)
  // balanced pairing: co-resident bid and bid+256 have complementary work
  const int qt = (bid < 256) ? (bid >> 3) : 63 - ((bid - 256) >> 3);
  const int b = bk >> 2;
  const int hl = wid & 3, qs = wid >> 2;
  const int h = (bk & 3) * G_ + hl;
  const int qrow0 = qt * 32 + qs * 16;
  const int l15 = lane & 15, g4 = lane >> 4, kk = g4 * 8;
  const int swz = (l15 & 7) << 4;

  // ---- fused Q: load + RMSNorm + RoPE (row = qrow0 + l15) ----
  const int qrow = qrow0 + l15;
  const bf16* qsrc = QKV + (size_t)(b * L_ + qrow) * NQKV_ + h * D_;
  float t[4][8];
  float ss = 0.f;
#pragma unroll
  for (int c = 0; c < 4; ++c) {
    bf16x8 v = *reinterpret_cast<const bf16x8*>(qsrc + c * 32 + kk);
#pragma unroll
    for (int j = 0; j < 8; ++j) { t[c][j] = (float)v[j]; ss += t[c][j] * t[c][j]; }
  }

  // staging coordinates (pre-swizzled global sources, linear LDS dest)
  const int kr0 = tid >> 4, kc0 = tid & 15;
  const int kr1 = 32 + kr0;
  const int vr0 = tid >> 3, vc0 = tid & 7;
  const int vr1 = 64 + vr0;
  const bf16* kb = Kn + (size_t)bk * L_ * D_;
  const bf16* vb = Vt + (size_t)bk * D_ * (size_t)L_;
  const bf16* kp0 = kb + (size_t)kr0 * D_ + ((kc0 ^ (kr0 & 7)) * 8);
  const bf16* kp1 = kb + (size_t)kr1 * D_ + ((kc0 ^ (kr1 & 7)) * 8);
  const bf16* vp0 = vb + (size_t)vr0 * L_ + ((vc0 ^ (vr0 & 7)) * 8);
  const bf16* vp1 = vb + (size_t)vr1 * L_ + ((vc0 ^ (vr1 & 7)) * 8);

  const int ntiles = ((qt >> 3) + 1) * 4;  // multiple of 4 -> kt-unroll-2 safe
  // prologue stage tile 0 -> buf 0 (flies while we do Q norm math)
  gload16(kp0, &sK[0][tid * 8]);
  gload16(kp1, &sK[0][(512 + tid) * 8]);
  gload16(vp0, &sV[0][tid * 8]);
  gload16(vp1, &sV[0][(512 + tid) * 8]);

  // Q norm math (overlaps staging); fold scale*log2e into Q fragments
  constexpr float SCL = 0.12752650038632816f;  // 128^-0.5 * log2(e)
  ss += __shfl_xor(ss, 16);
  ss += __shfl_xor(ss, 32);
  const float rr = rsqrtf(ss * (1.0f / 128.0f) + 1e-6f);
  bf16x8 qf[4];
#pragma unroll
  for (int c = 0; c < 2; ++c)
#pragma unroll
    for (int j = 0; j < 8; ++j) {
      int i = c * 32 + kk + j;
      float n1 = t[c][j] * rr * qnw[i];
      float n2 = t[c + 2][j] * rr * qnw[i + 64];
      float cs = cosb[qrow * 64 + i], sn = sinb[qrow * 64 + i];
      qf[c][j] = (bf16)((n1 * cs - n2 * sn) * SCL);
      qf[c + 2][j] = (bf16)((n2 * cs + n1 * sn) * SCL);
    }

  char* myP = (char*)(sP + wid * 16 * 64);
  f32x4 acc[8] = {};
  float mref = -1e30f, lpart = 0.f;

  __syncthreads();  // tile 0 staged (compiler drains vmcnt before barrier)

  // one kv-tile step; buffer choice is compile-time via manual unroll-2
  auto tile_step = [&](const bf16* sKc, const bf16* sVc, bf16* sKn_, bf16* sVn_,
                       int ktNext, bool doPref) {
    if (doPref) {
      gload16(kp0 + (size_t)ktNext * 64 * D_, &sKn_[tid * 8]);
      gload16(kp1 + (size_t)ktNext * 64 * D_, &sKn_[(512 + tid) * 8]);
      gload16(vp0 + ktNext * 64, &sVn_[tid * 8]);
      gload16(vp1 + ktNext * 64, &sVn_[(512 + tid) * 8]);
    }
    const char* cK = (const char*)sKc;
    const char* cV = (const char*)sVc;
    // --- swapped QK^T: s[n][r] = Sscaled[qrow=l15][key=16n+4g4+r] ---
    f32x4 s[4];
    __builtin_amdgcn_s_setprio(1);
#pragma unroll
    for (int n = 0; n < 4; ++n) {
      f32x4 st = {};
#pragma unroll
      for (int c = 0; c < 4; ++c) {
        int byte = (n * 16 + l15) * 256 + ((((c << 2) + g4) ^ (l15 & 7)) << 4);
        bf16x8 kf = *reinterpret_cast<const bf16x8*>(cK + byte);
        st = __builtin_amdgcn_mfma_f32_16x16x32_bf16(kf, qf[c], st, 0, 0, 0);
      }
      s[n] = st;
    }
    __builtin_amdgcn_s_setprio(0);
    // --- defer-max online softmax (scalar per lane: one q-row) ---
    float pm = fmaxf(fmaxf(s[0][0], s[0][1]), fmaxf(s[0][2], s[0][3]));
#pragma unroll
    for (int n = 1; n < 4; ++n)
      pm = fmaxf(pm, fmaxf(fmaxf(s[n][0], s[n][1]), fmaxf(s[n][2], s[n][3])));
    if (!__all(pm <= mref + 8.f)) {  // rare: true max grew -> reduce, rescale
      pm = fmaxf(pm, __shfl_xor(pm, 16));
      pm = fmaxf(pm, __shfl_xor(pm, 32));
      float mnew = fmaxf(mref, pm);
      float resc = exp2f(mref - mnew);
      mref = mnew;
      lpart *= resc;
#pragma unroll
      for (int f = 0; f < 8; ++f) acc[f] *= resc;
    }
#pragma unroll
    for (int n = 0; n < 4; ++n)
#pragma unroll
      for (int r = 0; r < 4; ++r) {
        float p = exp2f(s[n][r] - mref);
        s[n][r] = p;
        lpart += p;
      }
    // --- P -> LDS: 4 x ds_write_b64 (4 consecutive keys per reg group) ---
#pragma unroll
    for (int n = 0; n < 4; ++n) {
      bf16x4 pw = {(bf16)s[n][0], (bf16)s[n][1], (bf16)s[n][2], (bf16)s[n][3]};
      *reinterpret_cast<bf16x4*>(myP + l15 * 128 + (((n << 5) + (g4 << 3)) ^ swz)) = pw;
    }
    bf16x8 pf0 = *reinterpret_cast<const bf16x8*>(myP + l15 * 128 + ((g4 << 4) ^ swz));
    bf16x8 pf1 = *reinterpret_cast<const bf16x8*>(myP + l15 * 128 + ((64 + (g4 << 4)) ^ swz));
    // --- PV: O^T = mfma(V^T, P^T) ---
    __builtin_amdgcn_s_setprio(1);
#pragma unroll
    for (int f = 0; f < 8; ++f) {
      int d = f * 16 + l15;
      bf16x8 vf0 = *reinterpret_cast<const bf16x8*>(cV + d * 128 + ((g4 ^ (l15 & 7)) << 4));
      acc[f] = __builtin_amdgcn_mfma_f32_16x16x32_bf16(vf0, pf0, acc[f], 0, 0, 0);
      bf16x8 vf1 = *reinterpret_cast<const bf16x8*>(cV + d * 128 + (((4 + g4) ^ (l15 & 7)) << 4));
      acc[f] = __builtin_amdgcn_mfma_f32_16x16x32_bf16(vf1, pf1, acc[f], 0, 0, 0);
    }
    __builtin_amdgcn_s_setprio(0);
    __syncthreads();  // drains this iter's prefetch (late) + releases buffers
  };

  for (int kt = 0; kt < ntiles; kt += 2) {
    tile_step(sK[0], sV[0], sK[1], sV[1], kt + 1, true);
    tile_step(sK[1], sV[1], sK[0], sV[0], kt + 2, kt + 2 < ntiles);
  }

  // --- epilogue: reduce row-sum over the 4 lane-groups, packed stores ---
  lpart += __shfl_xor(lpart, 16);
  lpart += __shfl_xor(lpart, 32);
  const float rinv = 1.f / lpart;
  bf16* aop = AO + ((size_t)(b * L_ + qrow0 + l15) * H_ + h) * D_ + (g4 << 2);
#pragma unroll
  for (int f = 0; f < 8; ++f) {
    bf16x4 o = {(bf16)(acc[f][0] * rinv), (bf16)(acc[f][1] * rinv),
                (bf16)(acc[f][2] * rinv), (bf16)(acc[f][3] * rinv)};
    *reinterpret_cast<bf16x4*>(aop + f * 16) = o;
  }
}

// ---------------- launch ----------------
extern "C" void kernel_launch(void* const* d_in, const int* in_sizes, int n_in,
                              void* d_out, int out_size, void* d_ws, size_t ws_size,
                              hipStream_t stream) {
  const float* x = (const float*)d_in[0];
  const float* Wq = (const float*)d_in[1];
  const float* Wk = (const float*)d_in[2];
  const float* Wv = (const float*)d_in[3];
  const float* Wo = (const float*)d_in[4];
  const float* qnw = (const float*)d_in[5];
  const float* knw = (const float*)d_in[6];
  const float* rc = (const float*)d_in[7];
  const float* rs = (const float*)d_in[8];
  float* out = (float*)d_out;

  char* ws = (char*)d_ws;
  bf16* xb = (bf16*)ws;    ws += (size_t)TOK_ * C_ * 2;
  bf16* wqb = (bf16*)ws;   ws += (size_t)(H_ * D_) * C_ * 2;   // wq/wk/wv contiguous!
  bf16* wkb = (bf16*)ws;   ws += (size_t)(HKV_ * D_) * C_ * 2;
  bf16* wvb = (bf16*)ws;   ws += (size_t)(HKV_ * D_) * C_ * 2;
  bf16* wob = (bf16*)ws;   ws += (size_t)C_ * (H_ * D_) * 2;
  bf16* qkv = (bf16*)ws;   ws += (size_t)TOK_ * NQKV_ * 2;
  bf16* Kb = (bf16*)ws;    ws += (size_t)TOK_ * HKV_ * D_ * 2;
  bf16* Vtb = (bf16*)ws;   ws += (size_t)TOK_ * HKV_ * D_ * 2;
  bf16* AOb = xb;  // alias: xb dead after projection GEMM

  auto cvt = [&](const float* src, bf16* dst, size_t n) {
    int n4 = (int)(n / 4);
    int grid = (n4 + 255) / 256;
    if (grid > 4096) grid = 4096;
    cvt_bf16<<<grid, 256, 0, stream>>>(src, dst, n4);
  };
  cvt(x, xb, (size_t)TOK_ * C_);
  cvt(Wq, wqb, (size_t)H_ * D_ * C_);
  cvt(Wk, wkb, (size_t)HKV_ * D_ * C_);
  cvt(Wv, wvb, (size_t)HKV_ * D_ * C_);
  cvt(Wo, wob, (size_t)C_ * H_ * D_);

  // fused QKV projection: N = 3072 (wq,wk,wv rows contiguous)
  gemm_bt<false><<<dim3(TOK_ / 128, NQKV_ / 128), 256, 0, stream>>>(
      xb, wqb, qkv, TOK_, NQKV_, C_);

  k_norm_rope<<<(TOK_ * HKV_) / 4, 256, 0, stream>>>(qkv, knw, rc, rs, Kb);
  v_transpose<<<dim3(L_ / 64, B_ * HKV_), 256, 0, stream>>>(qkv, Vtb);

  attn_fused<<<512, 512, 0, stream>>>(qkv, Kb, Vtb, qnw, rc, rs, AOb);

  gemm_bt<true><<<dim3(TOK_ / 128, C_ / 128), 256, 0, stream>>>(
      AOb, wob, out, TOK_, C_, H_ * D_);
}